// Round 15
// baseline (306.400 us; speedup 1.0000x reference)
//
#include <hip/hip_runtime.h>
#include <hip/hip_bf16.h>
#include <math.h>

#define BSH 8          // 256 nodes per bucket
#define MAXBK 512      // >= nbk = ceil(N/256)
#define PCHUNK 4096    // edges per k_part block
#define BCSR_CAP 6144  // LDS-staged edges per bucket (48 KB)

typedef __attribute__((ext_vector_type(8)))  short short8;
typedef __attribute__((ext_vector_type(16))) float f32x16;

__device__ __forceinline__ float half_reduce_max(float v) {
  #pragma unroll
  for (int off = 16; off; off >>= 1) v = fmaxf(v, __shfl_xor(v, off));
  return v;
}
__device__ __forceinline__ float half_reduce_sum(float v) {
  #pragma unroll
  for (int off = 16; off; off >>= 1) v += __shfl_xor(v, off);
  return v;
}

// round-to-nearest-even f32 -> bf16 (as unsigned)
__device__ __forceinline__ unsigned f2bf(float f) {
  unsigned u = __float_as_uint(f);
  return (u + 0x7fffu + ((u >> 16) & 1u)) >> 16;
}
__device__ __forceinline__ float bf_lo(unsigned u) { return __uint_as_float(u << 16); }
__device__ __forceinline__ float bf_hi(unsigned u) { return __uint_as_float(u & 0xffff0000u); }

// async global->LDS, 16 B per lane (global_load_lds_dwordx4)
__device__ __forceinline__ void async_copy16(const void* gsrc, void* ldst) {
  __builtin_amdgcn_global_load_lds(
      (const __attribute__((address_space(1))) void*)gsrc,
      (__attribute__((address_space(3))) void*)ldst, 16, 0, 0);
}

// exclusive scan of arr[0..n) (n multiple of 64, <= MAXBK) by wave 0 of block
__device__ __forceinline__ void wave0_excl_scan(unsigned* arr, unsigned* out, int n, int t) {
  if (t < 64) {
    unsigned carry = 0;
    for (int c = 0; c < n / 64; c++) {
      unsigned v = arr[c * 64 + t];
      unsigned s = v;
      #pragma unroll
      for (int off = 1; off < 64; off <<= 1) {
        unsigned u = __shfl_up(s, off);
        if ((t & 63) >= off) s += u;
      }
      out[c * 64 + t] = s - v + carry;
      carry += __shfl(s, 63);
    }
  }
}

// ---------------- radix-bucketed CSR build (no global data atomics) -------

__global__ __launch_bounds__(256) void k_bhist(const int* __restrict__ ei,
                                               unsigned* __restrict__ gbucket,
                                               int E, int nbk) {
  __shared__ unsigned hist[MAXBK];
  int t = threadIdx.x;
  for (int i = t; i < nbk; i += 256) hist[i] = 0;
  __syncthreads();
  const int4* d4 = (const int4*)(ei + E);
  int nd4 = E >> 2;
  for (int i = blockIdx.x * 256 + t; i < nd4; i += gridDim.x * 256) {
    int4 d = d4[i];
    atomicAdd(&hist[d.x >> BSH], 1u);
    atomicAdd(&hist[d.y >> BSH], 1u);
    atomicAdd(&hist[d.z >> BSH], 1u);
    atomicAdd(&hist[d.w >> BSH], 1u);
  }
  if (blockIdx.x == 0) {
    for (int e = (nd4 << 2) + t; e < E; e += 256)
      atomicAdd(&hist[ei[E + e] >> BSH], 1u);
  }
  __syncthreads();
  for (int i = t; i < nbk; i += 256)
    if (hist[i]) atomicAdd(&gbucket[i], hist[i]);
}

// self-loop counts are analytic: bucket b holds min(256, N-256b) self loops
__global__ __launch_bounds__(256) void k_bscan(const unsigned* __restrict__ gbucket,
                                               unsigned* __restrict__ bbase,
                                               unsigned* __restrict__ bfill,
                                               int nbk, int EE, int Nn) {
  __shared__ unsigned arr[MAXBK], exc[MAXBK];
  int t = threadIdx.x;
  for (int i = t; i < MAXBK; i += 256) {
    unsigned v = 0;
    if (i < nbk) {
      int rem = Nn - (i << BSH);
      unsigned sl = rem >= 256 ? 256u : (unsigned)(rem > 0 ? rem : 0);
      v = gbucket[i] + sl;
    }
    arr[i] = v;
  }
  __syncthreads();
  wave0_excl_scan(arr, exc, MAXBK, t);
  __syncthreads();
  for (int i = t; i < nbk; i += 256) { bbase[i] = exc[i]; bfill[i] = exc[i]; }
  if (t == 0) bbase[nbk] = (unsigned)EE;
}

__global__ __launch_bounds__(256) void k_part(const int* __restrict__ ei,
                                              unsigned* __restrict__ bfill,
                                              uint2* __restrict__ part,
                                              int E, int EE) {
  __shared__ uint2 stage[PCHUNK];
  __shared__ unsigned lcnt[MAXBK], lexcl[MAXBK], lbase[MAXBK];
  int t = threadIdx.x;
  int base = blockIdx.x * PCHUNK;
  int cnt = EE - base; if (cnt > PCHUNK) cnt = PCHUNK;
  for (int i = t; i < MAXBK; i += 256) lcnt[i] = 0;
  __syncthreads();

  uint2 ed[16]; unsigned loc[16];
  #pragma unroll
  for (int i = 0; i < 16; i++) {
    int e = base + i * 256 + t;
    if (e < EE) {
      int s, d;
      if (e < E) { s = ei[e]; d = ei[E + e]; } else { s = e - E; d = s; }
      ed[i] = make_uint2((unsigned)s, (unsigned)d);
      loc[i] = atomicAdd(&lcnt[(unsigned)d >> BSH], 1u);
    }
  }
  __syncthreads();
  wave0_excl_scan(lcnt, lexcl, MAXBK, t);
  __syncthreads();
  for (int i = t; i < MAXBK; i += 256) {
    unsigned c = lcnt[i];
    lbase[i] = c ? atomicAdd(&bfill[i], c) : 0u;
  }
  __syncthreads();
  #pragma unroll
  for (int i = 0; i < 16; i++) {
    int e = base + i * 256 + t;
    if (e < EE) stage[lexcl[ed[i].y >> BSH] + loc[i]] = ed[i];
  }
  __syncthreads();
  for (int i = t; i < cnt; i += 256) {
    uint2 v = stage[i];
    unsigned b = v.y >> BSH;
    part[lbase[b] + ((unsigned)i - lexcl[b])] = v;
  }
}

__global__ __launch_bounds__(256) void k_bcsr(const uint2* __restrict__ part,
                                              const unsigned* __restrict__ bbase,
                                              int* __restrict__ rowptr,
                                              int* __restrict__ csr_src,
                                              int Nn, int nbk) {
  __shared__ unsigned sdeg[256], sexcl[256], sfill[256];
  __shared__ uint2 epart[BCSR_CAP];
  int t = threadIdx.x, b = blockIdx.x;
  int e0 = (int)bbase[b], e1 = (int)bbase[b + 1];
  int cnt = e1 - e0;
  bool fits = cnt <= BCSR_CAP;
  sdeg[t] = 0; sfill[t] = 0;
  __syncthreads();
  if (fits) {
    for (int j = t; j < cnt; j += 256) {
      uint2 v = part[e0 + j];
      epart[j] = v;
      atomicAdd(&sdeg[v.y & 255u], 1u);
    }
  } else {
    for (int j = e0 + t; j < e1; j += 256)
      atomicAdd(&sdeg[part[j].y & 255u], 1u);
  }
  __syncthreads();
  wave0_excl_scan(sdeg, sexcl, 256, t);
  __syncthreads();
  int node = (b << BSH) + t;
  if (node < Nn) rowptr[node] = e0 + (int)sexcl[t];
  if (b == nbk - 1 && t == 0) rowptr[Nn] = e1;
  if (fits) {
    for (int j = t; j < cnt; j += 256) {
      uint2 v = epart[j];
      unsigned dl = v.y & 255u;
      unsigned k = atomicAdd(&sfill[dl], 1u);
      csr_src[e0 + (int)sexcl[dl] + (int)k] = (int)v.x;
    }
  } else {
    for (int j = e0 + t; j < e1; j += 256) {
      uint2 v = part[j];
      unsigned dl = v.y & 255u;
      unsigned k = atomicAdd(&sfill[dl], 1u);
      csr_src[e0 + (int)sexcl[dl] + (int)k] = (int)v.x;
    }
  }
}

// ---------------- W fragment prep (frag-ordered bf16 for MFMA A-operand) --

__global__ __launch_bounds__(256) void k_wprep(const float* __restrict__ W1,
                                               const float* __restrict__ W2,
                                               const float* __restrict__ W3,
                                               short8* __restrict__ wf) {
  int idx = blockIdx.x * 256 + threadIdx.x;
  if (idx >= 2048) return;
  int g = idx >> 6, l = idx & 63;
  const float* W; int s, t;
  if (g < 16)      { W = W1; s = g >> 1;        t = g & 1; }
  else if (g < 24) { W = W2; s = (g - 16) >> 1; t = g & 1; }
  else             { W = W3; s = (g - 24) >> 1; t = g & 1; }
  int of = t * 32 + (l & 31);
  int k0 = s * 16 + (l >> 5) * 8;
  short8 v;
  #pragma unroll
  for (int e = 0; e < 8; e++) v[e] = (short)f2bf(W[(k0 + e) * 64 + of]);
  wf[idx] = v;
}

// ---------------- MFMA GEMM: h = x@W + fused alpha reductions -------------
// 128-thread/2-wave blocks, 64-row tiles, double-buffered LDS, grid-stride.

template <int K, bool F32IN>
__global__ __launch_bounds__(128) void k_gemm8(
    const void* __restrict__ xin, const short8* __restrict__ wf,
    const float* __restrict__ avs, const float* __restrict__ avd,
    unsigned* __restrict__ h, float* __restrict__ as_out,
    float* __restrict__ ad_out, int Nn, int ntiles) {
  constexpr int NS = K / 16;                 // k-steps
  constexpr int RB = F32IN ? K * 4 : K * 2;  // row bytes
  constexpr int RSH = F32IN ? 9 : (K == 128 ? 8 : 7);
  __shared__ __align__(16) char xs[2][64 * RB];
  int t = threadIdx.x, lane = t & 63, wid = t >> 6;   // wid in 0..1
  int l31 = lane & 31, hi = lane >> 5;

  short8 wa[NS * 2];
  #pragma unroll
  for (int i = 0; i < NS * 2; i++) wa[i] = wf[i * 64 + lane];

  const char* xg = (const char*)xin;
  auto stage = [&](int buf, int tl) {
    constexpr int CH = (64 * RB) / (128 * 16);
    #pragma unroll
    for (int i = 0; i < CH; i++) {
      int off = (i * 128 + t) * 16;
      int row = off >> RSH;
      int inrow = off & (RB - 1);
      long grow = (long)tl * 64 + row;
      if (grow > (long)Nn - 1) grow = Nn - 1;  // tail clamp (outputs guarded)
      async_copy16(xg + grow * RB + (inrow ^ ((row & 7) << 4)), xs[buf] + off);
    }
  };

  int tile = blockIdx.x;
  if (tile >= ntiles) return;
  stage(0, tile);
  __syncthreads();
  int buf = 0;

  while (tile < ntiles) {
    int nxt = tile + gridDim.x;
    if (nxt < ntiles) stage(buf ^ 1, nxt);

    f32x16 acc0 = {0,0,0,0,0,0,0,0,0,0,0,0,0,0,0,0};
    f32x16 acc1 = {0,0,0,0,0,0,0,0,0,0,0,0,0,0,0,0};
    int rowl = wid * 32 + l31;                 // 0..63
    int swz = (rowl & 7) << 4;
    const char* xb = xs[buf];

    #pragma unroll
    for (int s = 0; s < NS; s++) {
      short8 bf;
      if constexpr (F32IN) {
        int ph = (rowl * RB + s * 64 + hi * 32) ^ swz;
        float4 fA = *(const float4*)(xb + ph);
        float4 fB = *(const float4*)(xb + (ph ^ 16));
        bf[0] = (short)f2bf(fA.x); bf[1] = (short)f2bf(fA.y);
        bf[2] = (short)f2bf(fA.z); bf[3] = (short)f2bf(fA.w);
        bf[4] = (short)f2bf(fB.x); bf[5] = (short)f2bf(fB.y);
        bf[6] = (short)f2bf(fB.z); bf[7] = (short)f2bf(fB.w);
      } else {
        int ph = (rowl * RB + s * 32 + hi * 16) ^ swz;
        bf = *(const short8*)(xb + ph);
      }
      acc0 = __builtin_amdgcn_mfma_f32_32x32x16_bf16(wa[2 * s], bf, acc0, 0, 0, 0);
      acc1 = __builtin_amdgcn_mfma_f32_32x32x16_bf16(wa[2 * s + 1], bf, acc1, 0, 0, 0);
    }

    int xrow = tile * 64 + rowl;
    bool ok = xrow < Nn;
    float asp = 0.f, adp = 0.f;
    #pragma unroll
    for (int r = 0; r < 16; r += 2) {
      int rof = (r & 3) + 8 * (r >> 2);     // D row mapping (m74-verified)
      int of0 = rof + 4 * hi;
      if (ok) {
        h[(size_t)xrow * 32 + (of0 >> 1)] =
            (f2bf(acc0[r + 1]) << 16) | f2bf(acc0[r]);
        h[(size_t)xrow * 32 + 16 + (of0 >> 1)] =
            (f2bf(acc1[r + 1]) << 16) | f2bf(acc1[r]);
      }
      asp += acc0[r] * avs[of0] + acc0[r + 1] * avs[of0 + 1]
           + acc1[r] * avs[of0 + 32] + acc1[r + 1] * avs[of0 + 33];
      adp += acc0[r] * avd[of0] + acc0[r + 1] * avd[of0 + 1]
           + acc1[r] * avd[of0 + 32] + acc1[r + 1] * avd[of0 + 33];
    }
    asp += __shfl_xor(asp, 32);
    adp += __shfl_xor(adp, 32);
    if (ok && hi == 0) { as_out[xrow] = asp; ad_out[xrow] = adp; }

    __syncthreads();
    buf ^= 1;
    tile = nxt;
  }
}

// ---------------- per-dst-node softmax aggregation ----------------
// Half-wave per node; uint4 phase-B gathers (4 edges/instr). Grid-stride
// persistent blocks (no internal barriers -> loop is free) to eliminate
// workgroup launch/drain churn.

template <int FINAL>
__global__ __launch_bounds__(256) void k_agg12(
    const int* __restrict__ rowptr, const int* __restrict__ csr_src,
    const unsigned* __restrict__ hp, const float* __restrict__ as_,
    const float* __restrict__ ad_, const float* __restrict__ bias,
    unsigned* __restrict__ out, const float* __restrict__ Wlin,
    const float* __restrict__ blin, float* __restrict__ fout,
    int Nn, int ngroups) {
  __shared__ float2 psbuf[4][2][32];
  int t = threadIdx.x, lane = t & 63, wid = t >> 6;
  int fl = lane & 31, hh = lane >> 5;

  for (int grp = blockIdx.x; grp < ngroups; grp += gridDim.x) {
    int n = grp * 8 + wid * 2 + hh;
    bool valid = n < Nn;
    int nn = valid ? n : (Nn - 1);
    int r0 = rowptr[nn], r1 = rowptr[nn + 1];
    int deg = valid ? (r1 - r0) : 0;
    float ad = ad_[nn];

    if (deg <= 32) {
      // phase A: edge-parallel scores + softmax (32 lanes)
      int src = (fl < deg) ? csr_src[r0 + fl] : 0;
      float e = (fl < deg) ? (as_[src] + ad) : -3.0e38f;
      e = (e >= 0.f) ? e : 0.2f * e;
      float m = half_reduce_max(e);
      float p = (fl < deg) ? __expf(e - m) : 0.f;
      float inv = 1.f / (half_reduce_sum(p) + 1e-16f);
      psbuf[wid][hh][fl] = make_float2(p, __uint_as_float((unsigned)src * 128u));

      // phase B: 4 edges per gather instruction (8 lanes/edge)
      int sub = fl >> 3, oc = fl & 7;
      const char* hq = (const char*)hp + oc * 16;
      const float2* psb = psbuf[wid][hh];

      float pp[8];
      uint4 vv[8];
      #pragma unroll
      for (int it = 0; it < 8; it++) {
        if (it * 4 < deg) {
          float2 ps = psb[it * 4 + sub];
          pp[it] = ps.x;
          vv[it] = *(const uint4*)(hq + __float_as_uint(ps.y));
        }
      }
      float a0 = 0.f, a1 = 0.f, a2 = 0.f, a3 = 0.f;
      float a4 = 0.f, a5 = 0.f, a6 = 0.f, a7 = 0.f;
      #pragma unroll
      for (int it = 0; it < 8; it++) {
        if (it * 4 < deg) {
          a0 = fmaf(pp[it], bf_lo(vv[it].x), a0);
          a1 = fmaf(pp[it], bf_hi(vv[it].x), a1);
          a2 = fmaf(pp[it], bf_lo(vv[it].y), a2);
          a3 = fmaf(pp[it], bf_hi(vv[it].y), a3);
          a4 = fmaf(pp[it], bf_lo(vv[it].z), a4);
          a5 = fmaf(pp[it], bf_hi(vv[it].z), a5);
          a6 = fmaf(pp[it], bf_lo(vv[it].w), a6);
          a7 = fmaf(pp[it], bf_hi(vv[it].w), a7);
        }
      }
      #pragma unroll
      for (int off = 8; off <= 16; off <<= 1) {   // combine edge slots
        a0 += __shfl_xor(a0, off);
        a1 += __shfl_xor(a1, off);
        a2 += __shfl_xor(a2, off);
        a3 += __shfl_xor(a3, off);
        a4 += __shfl_xor(a4, off);
        a5 += __shfl_xor(a5, off);
        a6 += __shfl_xor(a6, off);
        a7 += __shfl_xor(a7, off);
      }

      float4 biA = ((const float4*)bias)[2 * oc];
      float4 biB = ((const float4*)bias)[2 * oc + 1];
      float o0 = fmaxf(fmaf(a0, inv, biA.x), 0.f);
      float o1 = fmaxf(fmaf(a1, inv, biA.y), 0.f);
      float o2 = fmaxf(fmaf(a2, inv, biA.z), 0.f);
      float o3 = fmaxf(fmaf(a3, inv, biA.w), 0.f);
      float o4 = fmaxf(fmaf(a4, inv, biB.x), 0.f);
      float o5 = fmaxf(fmaf(a5, inv, biB.y), 0.f);
      float o6 = fmaxf(fmaf(a6, inv, biB.z), 0.f);
      float o7 = fmaxf(fmaf(a7, inv, biB.w), 0.f);
      if (FINAL) {
        float4 wlA = ((const float4*)Wlin)[2 * oc];
        float4 wlB = ((const float4*)Wlin)[2 * oc + 1];
        float rv = (sub == 0)
            ? (o0 * wlA.x + o1 * wlA.y + o2 * wlA.z + o3 * wlA.w +
               o4 * wlB.x + o5 * wlB.y + o6 * wlB.z + o7 * wlB.w) : 0.f;
        rv = half_reduce_sum(rv);
        if (valid && fl == 0) {
          float z = rv + blin[0];
          fout[n] = 1.f / (1.f + __expf(-z));
        }
      } else if (valid && sub == 0) {
        uint4 pk;
        pk.x = (f2bf(o1) << 16) | f2bf(o0);
        pk.y = (f2bf(o3) << 16) | f2bf(o2);
        pk.z = (f2bf(o5) << 16) | f2bf(o4);
        pk.w = (f2bf(o7) << 16) | f2bf(o6);
        *(uint4*)(out + (size_t)n * 32 + 4 * oc) = pk;
      }
    } else {
      // rare fallback (deg > 32): two-pass, serial recompute
      float acc0 = 0.f, acc1 = 0.f;
      float m = -3.0e38f;
      for (int j = r0 + fl; j < r1; j += 32) {
        float e = as_[csr_src[j]] + ad;
        e = (e >= 0.f) ? e : 0.2f * e;
        m = fmaxf(m, e);
      }
      m = half_reduce_max(m);
      float ssum = 0.f;
      for (int j = r0; j < r1; ++j) {
        int src = csr_src[j];
        float e = as_[src] + ad;
        e = (e >= 0.f) ? e : 0.2f * e;
        float p = __expf(e - m);
        ssum += p;
        unsigned v = hp[(size_t)src * 32 + fl];
        acc0 = fmaf(p, bf_lo(v), acc0);
        acc1 = fmaf(p, bf_hi(v), acc1);
      }
      float inv2 = 1.f / (ssum + 1e-16f);
      acc0 *= inv2;
      acc1 *= inv2;
      float2 bi = ((const float2*)bias)[fl];
      float o0 = fmaxf(acc0 + bi.x, 0.f);
      float o1 = fmaxf(acc1 + bi.y, 0.f);
      if (FINAL) {
        float2 wl = ((const float2*)Wlin)[fl];
        float rv = half_reduce_sum(o0 * wl.x + o1 * wl.y);
        if (valid && fl == 0) {
          float z = rv + blin[0];
          fout[n] = 1.f / (1.f + __expf(-z));
        }
      } else {
        if (valid) out[(size_t)n * 32 + fl] = (f2bf(o1) << 16) | f2bf(o0);
      }
    }
  }
}

extern "C" void kernel_launch(void* const* d_in, const int* in_sizes, int n_in,
                              void* d_out, int out_size, void* d_ws, size_t ws_size,
                              hipStream_t stream) {
  const float* x   = (const float*)d_in[0];
  const int*   ei  = (const int*)d_in[1];
  const float* W1  = (const float*)d_in[2];
  const float* a1s = (const float*)d_in[3];
  const float* a1d = (const float*)d_in[4];
  const float* b1  = (const float*)d_in[5];
  const float* W2  = (const float*)d_in[6];
  const float* a2s = (const float*)d_in[7];
  const float* a2d = (const float*)d_in[8];
  const float* b2  = (const float*)d_in[9];
  const float* W3  = (const float*)d_in[10];
  const float* a3s = (const float*)d_in[11];
  const float* a3d = (const float*)d_in[12];
  const float* b3  = (const float*)d_in[13];
  const float* Wl  = (const float*)d_in[14];
  const float* bl  = (const float*)d_in[15];

  const int N  = in_sizes[0] / 128;
  const int E  = in_sizes[1] / 2;
  const int EE = E + N;
  const int nbk = (N + 255) >> 8;

  char* p = (char*)d_ws;
  auto alloc = [&](size_t bytes) { char* r = p; p += (bytes + 255) & ~(size_t)255; return r; };
  unsigned* gbucket = (unsigned*)alloc((size_t)MAXBK * 4);
  unsigned* bbase   = (unsigned*)alloc((size_t)(MAXBK + 1) * 4);
  unsigned* bfill   = (unsigned*)alloc((size_t)MAXBK * 4);
  short8*   wf      = (short8*)alloc(2048 * 16);
  int*      rowptr  = (int*)alloc((size_t)(N + 1) * 4);
  int*      csr_src = (int*)alloc((size_t)EE * 4);
  unsigned* hbuf    = (unsigned*)alloc((size_t)N * 32 * 4);   // bf16-pair packed
  char*     regionA = alloc((size_t)EE * 8);                  // part[] then obuf
  float*    as_     = (float*)alloc((size_t)N * 4);
  float*    ad_     = (float*)alloc((size_t)N * 4);

  uint2*    part = (uint2*)regionA;            // CSR build scratch
  unsigned* obuf = (unsigned*)regionA;         // bf16-pair packed layer io

  hipMemsetAsync(gbucket, 0, (size_t)MAXBK * 4, stream);

  k_wprep<<<8, 256, 0, stream>>>(W1, W2, W3, wf);
  k_bhist<<<256, 256, 0, stream>>>(ei, gbucket, E, nbk);
  k_bscan<<<1, 256, 0, stream>>>(gbucket, bbase, bfill, nbk, EE, N);
  k_part<<<(EE + PCHUNK - 1) / PCHUNK, 256, 0, stream>>>(ei, bfill, part, E, EE);
  k_bcsr<<<nbk, 256, 0, stream>>>(part, bbase, rowptr, csr_src, N, nbk);

  int ntile64 = (N + 63) / 64;
  int g1 = ntile64 < 512 ? ntile64 : 512;
  int g2 = ntile64 < 768 ? ntile64 : 768;
  int ngroups = (N + 7) / 8;
  int ga = ngroups < 1536 ? ngroups : 1536;

  // layer 1 (f32 x input, K=128)
  k_gemm8<128, true><<<g1, 128, 0, stream>>>(x, wf, a1s, a1d, hbuf, as_, ad_, N, ntile64);
  k_agg12<0><<<ga, 256, 0, stream>>>(rowptr, csr_src, hbuf, as_, ad_, b1, obuf,
                                     nullptr, nullptr, nullptr, N, ngroups);
  // layer 2 (bf16 obuf input, K=64)
  k_gemm8<64, false><<<g2, 128, 0, stream>>>(obuf, wf + 16 * 64, a2s, a2d,
                                             hbuf, as_, ad_, N, ntile64);
  k_agg12<0><<<ga, 256, 0, stream>>>(rowptr, csr_src, hbuf, as_, ad_, b2, obuf,
                                     nullptr, nullptr, nullptr, N, ngroups);
  // layer 3 (+ fused readout)
  k_gemm8<64, false><<<g2, 128, 0, stream>>>(obuf, wf + 24 * 64, a3s, a3d,
                                             hbuf, as_, ad_, N, ntile64);
  k_agg12<1><<<ga, 256, 0, stream>>>(rowptr, csr_src, hbuf, as_, ad_, b3, nullptr,
                                     Wl, bl, (float*)d_out, N, ngroups);
}

// Round 16
// 238.062 us; speedup vs baseline: 1.2871x; 1.2871x over previous
//
#include <hip/hip_runtime.h>
#include <hip/hip_bf16.h>
#include <math.h>

#define BSH 8          // 256 nodes per bucket
#define MAXBK 512      // >= nbk = ceil(N/256)
#define PCHUNK 4096    // edges per k_part block
#define BCSR_CAP 6144  // LDS-staged edges per bucket (48 KB)

typedef __attribute__((ext_vector_type(8)))  short short8;
typedef __attribute__((ext_vector_type(16))) float f32x16;

__device__ __forceinline__ float half_reduce_max(float v) {
  #pragma unroll
  for (int off = 16; off; off >>= 1) v = fmaxf(v, __shfl_xor(v, off));
  return v;
}
__device__ __forceinline__ float half_reduce_sum(float v) {
  #pragma unroll
  for (int off = 16; off; off >>= 1) v += __shfl_xor(v, off);
  return v;
}

// round-to-nearest-even f32 -> bf16 (as unsigned)
__device__ __forceinline__ unsigned f2bf(float f) {
  unsigned u = __float_as_uint(f);
  return (u + 0x7fffu + ((u >> 16) & 1u)) >> 16;
}
__device__ __forceinline__ float bf_lo(unsigned u) { return __uint_as_float(u << 16); }
__device__ __forceinline__ float bf_hi(unsigned u) { return __uint_as_float(u & 0xffff0000u); }

// async global->LDS, 16 B per lane (global_load_lds_dwordx4)
__device__ __forceinline__ void async_copy16(const void* gsrc, void* ldst) {
  __builtin_amdgcn_global_load_lds(
      (const __attribute__((address_space(1))) void*)gsrc,
      (__attribute__((address_space(3))) void*)ldst, 16, 0, 0);
}

// exclusive scan of arr[0..n) (n multiple of 64, <= MAXBK) by wave 0 of block
__device__ __forceinline__ void wave0_excl_scan(unsigned* arr, unsigned* out, int n, int t) {
  if (t < 64) {
    unsigned carry = 0;
    for (int c = 0; c < n / 64; c++) {
      unsigned v = arr[c * 64 + t];
      unsigned s = v;
      #pragma unroll
      for (int off = 1; off < 64; off <<= 1) {
        unsigned u = __shfl_up(s, off);
        if ((t & 63) >= off) s += u;
      }
      out[c * 64 + t] = s - v + carry;
      carry += __shfl(s, 63);
    }
  }
}

// ---------------- radix-bucketed CSR build (no global data atomics) -------

__global__ __launch_bounds__(256) void k_bhist(const int* __restrict__ ei,
                                               unsigned* __restrict__ gbucket,
                                               int E, int nbk) {
  __shared__ unsigned hist[MAXBK];
  int t = threadIdx.x;
  for (int i = t; i < nbk; i += 256) hist[i] = 0;
  __syncthreads();
  const int4* d4 = (const int4*)(ei + E);
  int nd4 = E >> 2;
  for (int i = blockIdx.x * 256 + t; i < nd4; i += gridDim.x * 256) {
    int4 d = d4[i];
    atomicAdd(&hist[d.x >> BSH], 1u);
    atomicAdd(&hist[d.y >> BSH], 1u);
    atomicAdd(&hist[d.z >> BSH], 1u);
    atomicAdd(&hist[d.w >> BSH], 1u);
  }
  if (blockIdx.x == 0) {
    for (int e = (nd4 << 2) + t; e < E; e += 256)
      atomicAdd(&hist[ei[E + e] >> BSH], 1u);
  }
  __syncthreads();
  for (int i = t; i < nbk; i += 256)
    if (hist[i]) atomicAdd(&gbucket[i], hist[i]);
}

// self-loop counts are analytic: bucket b holds min(256, N-256b) self loops
__global__ __launch_bounds__(256) void k_bscan(const unsigned* __restrict__ gbucket,
                                               unsigned* __restrict__ bbase,
                                               unsigned* __restrict__ bfill,
                                               int nbk, int EE, int Nn) {
  __shared__ unsigned arr[MAXBK], exc[MAXBK];
  int t = threadIdx.x;
  for (int i = t; i < MAXBK; i += 256) {
    unsigned v = 0;
    if (i < nbk) {
      int rem = Nn - (i << BSH);
      unsigned sl = rem >= 256 ? 256u : (unsigned)(rem > 0 ? rem : 0);
      v = gbucket[i] + sl;
    }
    arr[i] = v;
  }
  __syncthreads();
  wave0_excl_scan(arr, exc, MAXBK, t);
  __syncthreads();
  for (int i = t; i < nbk; i += 256) { bbase[i] = exc[i]; bfill[i] = exc[i]; }
  if (t == 0) bbase[nbk] = (unsigned)EE;
}

__global__ __launch_bounds__(256) void k_part(const int* __restrict__ ei,
                                              unsigned* __restrict__ bfill,
                                              uint2* __restrict__ part,
                                              int E, int EE) {
  __shared__ uint2 stage[PCHUNK];
  __shared__ unsigned lcnt[MAXBK], lexcl[MAXBK], lbase[MAXBK];
  int t = threadIdx.x;
  int base = blockIdx.x * PCHUNK;
  int cnt = EE - base; if (cnt > PCHUNK) cnt = PCHUNK;
  for (int i = t; i < MAXBK; i += 256) lcnt[i] = 0;
  __syncthreads();

  uint2 ed[16]; unsigned loc[16];
  #pragma unroll
  for (int i = 0; i < 16; i++) {
    int e = base + i * 256 + t;
    if (e < EE) {
      int s, d;
      if (e < E) { s = ei[e]; d = ei[E + e]; } else { s = e - E; d = s; }
      ed[i] = make_uint2((unsigned)s, (unsigned)d);
      loc[i] = atomicAdd(&lcnt[(unsigned)d >> BSH], 1u);
    }
  }
  __syncthreads();
  wave0_excl_scan(lcnt, lexcl, MAXBK, t);
  __syncthreads();
  for (int i = t; i < MAXBK; i += 256) {
    unsigned c = lcnt[i];
    lbase[i] = c ? atomicAdd(&bfill[i], c) : 0u;
  }
  __syncthreads();
  #pragma unroll
  for (int i = 0; i < 16; i++) {
    int e = base + i * 256 + t;
    if (e < EE) stage[lexcl[ed[i].y >> BSH] + loc[i]] = ed[i];
  }
  __syncthreads();
  for (int i = t; i < cnt; i += 256) {
    uint2 v = stage[i];
    unsigned b = v.y >> BSH;
    part[lbase[b] + ((unsigned)i - lexcl[b])] = v;
  }
}

__global__ __launch_bounds__(256) void k_bcsr(const uint2* __restrict__ part,
                                              const unsigned* __restrict__ bbase,
                                              int* __restrict__ rowptr,
                                              int* __restrict__ csr_src,
                                              int Nn, int nbk) {
  __shared__ unsigned sdeg[256], sexcl[256], sfill[256];
  __shared__ uint2 epart[BCSR_CAP];
  int t = threadIdx.x, b = blockIdx.x;
  int e0 = (int)bbase[b], e1 = (int)bbase[b + 1];
  int cnt = e1 - e0;
  bool fits = cnt <= BCSR_CAP;
  sdeg[t] = 0; sfill[t] = 0;
  __syncthreads();
  if (fits) {
    for (int j = t; j < cnt; j += 256) {
      uint2 v = part[e0 + j];
      epart[j] = v;
      atomicAdd(&sdeg[v.y & 255u], 1u);
    }
  } else {
    for (int j = e0 + t; j < e1; j += 256)
      atomicAdd(&sdeg[part[j].y & 255u], 1u);
  }
  __syncthreads();
  wave0_excl_scan(sdeg, sexcl, 256, t);
  __syncthreads();
  int node = (b << BSH) + t;
  if (node < Nn) rowptr[node] = e0 + (int)sexcl[t];
  if (b == nbk - 1 && t == 0) rowptr[Nn] = e1;
  if (fits) {
    for (int j = t; j < cnt; j += 256) {
      uint2 v = epart[j];
      unsigned dl = v.y & 255u;
      unsigned k = atomicAdd(&sfill[dl], 1u);
      csr_src[e0 + (int)sexcl[dl] + (int)k] = (int)v.x;
    }
  } else {
    for (int j = e0 + t; j < e1; j += 256) {
      uint2 v = part[j];
      unsigned dl = v.y & 255u;
      unsigned k = atomicAdd(&sfill[dl], 1u);
      csr_src[e0 + (int)sexcl[dl] + (int)k] = (int)v.x;
    }
  }
}

// ---------------- W fragment prep (frag-ordered bf16 for MFMA A-operand) --

__global__ __launch_bounds__(256) void k_wprep(const float* __restrict__ W1,
                                               const float* __restrict__ W2,
                                               const float* __restrict__ W3,
                                               short8* __restrict__ wf) {
  int idx = blockIdx.x * 256 + threadIdx.x;
  if (idx >= 2048) return;
  int g = idx >> 6, l = idx & 63;
  const float* W; int s, t;
  if (g < 16)      { W = W1; s = g >> 1;        t = g & 1; }
  else if (g < 24) { W = W2; s = (g - 16) >> 1; t = g & 1; }
  else             { W = W3; s = (g - 24) >> 1; t = g & 1; }
  int of = t * 32 + (l & 31);
  int k0 = s * 16 + (l >> 5) * 8;
  short8 v;
  #pragma unroll
  for (int e = 0; e < 8; e++) v[e] = (short)f2bf(W[(k0 + e) * 64 + of]);
  wf[idx] = v;
}

// ---------------- MFMA GEMM: h = x@W + fused alpha reductions -------------
// 128-thread/2-wave blocks, 64-row tiles, double-buffered LDS, grid-stride.

template <int K, bool F32IN>
__global__ __launch_bounds__(128) void k_gemm8(
    const void* __restrict__ xin, const short8* __restrict__ wf,
    const float* __restrict__ avs, const float* __restrict__ avd,
    unsigned* __restrict__ h, float* __restrict__ as_out,
    float* __restrict__ ad_out, int Nn, int ntiles) {
  constexpr int NS = K / 16;                 // k-steps
  constexpr int RB = F32IN ? K * 4 : K * 2;  // row bytes
  constexpr int RSH = F32IN ? 9 : (K == 128 ? 8 : 7);
  __shared__ __align__(16) char xs[2][64 * RB];
  int t = threadIdx.x, lane = t & 63, wid = t >> 6;   // wid in 0..1
  int l31 = lane & 31, hi = lane >> 5;

  short8 wa[NS * 2];
  #pragma unroll
  for (int i = 0; i < NS * 2; i++) wa[i] = wf[i * 64 + lane];

  const char* xg = (const char*)xin;
  auto stage = [&](int buf, int tl) {
    constexpr int CH = (64 * RB) / (128 * 16);
    #pragma unroll
    for (int i = 0; i < CH; i++) {
      int off = (i * 128 + t) * 16;
      int row = off >> RSH;
      int inrow = off & (RB - 1);
      long grow = (long)tl * 64 + row;
      if (grow > (long)Nn - 1) grow = Nn - 1;  // tail clamp (outputs guarded)
      async_copy16(xg + grow * RB + (inrow ^ ((row & 7) << 4)), xs[buf] + off);
    }
  };

  int tile = blockIdx.x;
  if (tile >= ntiles) return;
  stage(0, tile);
  __syncthreads();
  int buf = 0;

  while (tile < ntiles) {
    int nxt = tile + gridDim.x;
    if (nxt < ntiles) stage(buf ^ 1, nxt);

    f32x16 acc0 = {0,0,0,0,0,0,0,0,0,0,0,0,0,0,0,0};
    f32x16 acc1 = {0,0,0,0,0,0,0,0,0,0,0,0,0,0,0,0};
    int rowl = wid * 32 + l31;                 // 0..63
    int swz = (rowl & 7) << 4;
    const char* xb = xs[buf];

    #pragma unroll
    for (int s = 0; s < NS; s++) {
      short8 bf;
      if constexpr (F32IN) {
        int ph = (rowl * RB + s * 64 + hi * 32) ^ swz;
        float4 fA = *(const float4*)(xb + ph);
        float4 fB = *(const float4*)(xb + (ph ^ 16));
        bf[0] = (short)f2bf(fA.x); bf[1] = (short)f2bf(fA.y);
        bf[2] = (short)f2bf(fA.z); bf[3] = (short)f2bf(fA.w);
        bf[4] = (short)f2bf(fB.x); bf[5] = (short)f2bf(fB.y);
        bf[6] = (short)f2bf(fB.z); bf[7] = (short)f2bf(fB.w);
      } else {
        int ph = (rowl * RB + s * 32 + hi * 16) ^ swz;
        bf = *(const short8*)(xb + ph);
      }
      acc0 = __builtin_amdgcn_mfma_f32_32x32x16_bf16(wa[2 * s], bf, acc0, 0, 0, 0);
      acc1 = __builtin_amdgcn_mfma_f32_32x32x16_bf16(wa[2 * s + 1], bf, acc1, 0, 0, 0);
    }

    int xrow = tile * 64 + rowl;
    bool ok = xrow < Nn;
    float asp = 0.f, adp = 0.f;
    #pragma unroll
    for (int r = 0; r < 16; r += 2) {
      int rof = (r & 3) + 8 * (r >> 2);     // D row mapping (m74-verified)
      int of0 = rof + 4 * hi;
      if (ok) {
        h[(size_t)xrow * 32 + (of0 >> 1)] =
            (f2bf(acc0[r + 1]) << 16) | f2bf(acc0[r]);
        h[(size_t)xrow * 32 + 16 + (of0 >> 1)] =
            (f2bf(acc1[r + 1]) << 16) | f2bf(acc1[r]);
      }
      asp += acc0[r] * avs[of0] + acc0[r + 1] * avs[of0 + 1]
           + acc1[r] * avs[of0 + 32] + acc1[r + 1] * avs[of0 + 33];
      adp += acc0[r] * avd[of0] + acc0[r + 1] * avd[of0 + 1]
           + acc1[r] * avd[of0 + 32] + acc1[r + 1] * avd[of0 + 33];
    }
    asp += __shfl_xor(asp, 32);
    adp += __shfl_xor(adp, 32);
    if (ok && hi == 0) { as_out[xrow] = asp; ad_out[xrow] = adp; }

    __syncthreads();
    buf ^= 1;
    tile = nxt;
  }
}

// ---------------- per-dst-node softmax aggregation ----------------
// Half-wave per node. Phase B: uint4 gathers — 8 lanes cover one 128-B edge
// row, so one half-wave instruction fetches FOUR edges (sub = fl>>3 edge
// slot, oc = fl&7 row octant). Per node: <=4 gather rounds of 4 edges.
// Combine across edge slots via shfl_xor(8)+shfl_xor(16).

template <int FINAL>
__global__ __launch_bounds__(256) void k_agg11(
    const int* __restrict__ rowptr, const int* __restrict__ csr_src,
    const unsigned* __restrict__ hp, const float* __restrict__ as_,
    const float* __restrict__ ad_, const float* __restrict__ bias,
    unsigned* __restrict__ out, const float* __restrict__ Wlin,
    const float* __restrict__ blin, float* __restrict__ fout, int Nn) {
  __shared__ float2 psbuf[4][2][32];
  int t = threadIdx.x, lane = t & 63, wid = t >> 6;
  int fl = lane & 31, hh = lane >> 5;
  int n = blockIdx.x * 8 + wid * 2 + hh;
  bool valid = n < Nn;
  int nn = valid ? n : (Nn - 1);
  int r0 = rowptr[nn], r1 = rowptr[nn + 1];
  int deg = valid ? (r1 - r0) : 0;
  float ad = ad_[nn];

  if (deg <= 32) {
    // phase A: edge-parallel scores + softmax (32 lanes)
    int src = (fl < deg) ? csr_src[r0 + fl] : 0;
    float e = (fl < deg) ? (as_[src] + ad) : -3.0e38f;
    e = (e >= 0.f) ? e : 0.2f * e;
    float m = half_reduce_max(e);
    float p = (fl < deg) ? __expf(e - m) : 0.f;
    float inv = 1.f / (half_reduce_sum(p) + 1e-16f);
    psbuf[wid][hh][fl] = make_float2(p, __uint_as_float((unsigned)src * 128u));

    // phase B: 4 edges per gather instruction (8 lanes/edge)
    int sub = fl >> 3, oc = fl & 7;
    const char* hq = (const char*)hp + oc * 16;
    const float2* psb = psbuf[wid][hh];

    float pp[8];
    uint4 vv[8];
    #pragma unroll
    for (int it = 0; it < 8; it++) {
      if (it * 4 < deg) {
        float2 ps = psb[it * 4 + sub];
        pp[it] = ps.x;
        vv[it] = *(const uint4*)(hq + __float_as_uint(ps.y));
      }
    }
    float a0 = 0.f, a1 = 0.f, a2 = 0.f, a3 = 0.f;
    float a4 = 0.f, a5 = 0.f, a6 = 0.f, a7 = 0.f;
    #pragma unroll
    for (int it = 0; it < 8; it++) {
      if (it * 4 < deg) {
        a0 = fmaf(pp[it], bf_lo(vv[it].x), a0);
        a1 = fmaf(pp[it], bf_hi(vv[it].x), a1);
        a2 = fmaf(pp[it], bf_lo(vv[it].y), a2);
        a3 = fmaf(pp[it], bf_hi(vv[it].y), a3);
        a4 = fmaf(pp[it], bf_lo(vv[it].z), a4);
        a5 = fmaf(pp[it], bf_hi(vv[it].z), a5);
        a6 = fmaf(pp[it], bf_lo(vv[it].w), a6);
        a7 = fmaf(pp[it], bf_hi(vv[it].w), a7);
      }
    }
    #pragma unroll
    for (int off = 8; off <= 16; off <<= 1) {   // combine edge slots
      a0 += __shfl_xor(a0, off);
      a1 += __shfl_xor(a1, off);
      a2 += __shfl_xor(a2, off);
      a3 += __shfl_xor(a3, off);
      a4 += __shfl_xor(a4, off);
      a5 += __shfl_xor(a5, off);
      a6 += __shfl_xor(a6, off);
      a7 += __shfl_xor(a7, off);
    }

    float4 biA = ((const float4*)bias)[2 * oc];
    float4 biB = ((const float4*)bias)[2 * oc + 1];
    float o0 = fmaxf(fmaf(a0, inv, biA.x), 0.f);
    float o1 = fmaxf(fmaf(a1, inv, biA.y), 0.f);
    float o2 = fmaxf(fmaf(a2, inv, biA.z), 0.f);
    float o3 = fmaxf(fmaf(a3, inv, biA.w), 0.f);
    float o4 = fmaxf(fmaf(a4, inv, biB.x), 0.f);
    float o5 = fmaxf(fmaf(a5, inv, biB.y), 0.f);
    float o6 = fmaxf(fmaf(a6, inv, biB.z), 0.f);
    float o7 = fmaxf(fmaf(a7, inv, biB.w), 0.f);
    if (FINAL) {
      float4 wlA = ((const float4*)Wlin)[2 * oc];
      float4 wlB = ((const float4*)Wlin)[2 * oc + 1];
      float rv = (sub == 0)
          ? (o0 * wlA.x + o1 * wlA.y + o2 * wlA.z + o3 * wlA.w +
             o4 * wlB.x + o5 * wlB.y + o6 * wlB.z + o7 * wlB.w) : 0.f;
      rv = half_reduce_sum(rv);
      if (valid && fl == 0) {
        float z = rv + blin[0];
        fout[n] = 1.f / (1.f + __expf(-z));
      }
    } else if (valid && sub == 0) {
      uint4 pk;
      pk.x = (f2bf(o1) << 16) | f2bf(o0);
      pk.y = (f2bf(o3) << 16) | f2bf(o2);
      pk.z = (f2bf(o5) << 16) | f2bf(o4);
      pk.w = (f2bf(o7) << 16) | f2bf(o6);
      *(uint4*)(out + (size_t)n * 32 + 4 * oc) = pk;
    }
  } else {
    // rare fallback (deg > 32): two-pass, serial recompute
    float acc0 = 0.f, acc1 = 0.f;
    float m = -3.0e38f;
    for (int j = r0 + fl; j < r1; j += 32) {
      float e = as_[csr_src[j]] + ad;
      e = (e >= 0.f) ? e : 0.2f * e;
      m = fmaxf(m, e);
    }
    m = half_reduce_max(m);
    float ssum = 0.f;
    for (int j = r0; j < r1; ++j) {
      int src = csr_src[j];
      float e = as_[src] + ad;
      e = (e >= 0.f) ? e : 0.2f * e;
      float p = __expf(e - m);
      ssum += p;
      unsigned v = hp[(size_t)src * 32 + fl];
      acc0 = fmaf(p, bf_lo(v), acc0);
      acc1 = fmaf(p, bf_hi(v), acc1);
    }
    float inv2 = 1.f / (ssum + 1e-16f);
    acc0 *= inv2;
    acc1 *= inv2;
    float2 bi = ((const float2*)bias)[fl];
    float o0 = fmaxf(acc0 + bi.x, 0.f);
    float o1 = fmaxf(acc1 + bi.y, 0.f);
    if (FINAL) {
      float2 wl = ((const float2*)Wlin)[fl];
      float rv = half_reduce_sum(o0 * wl.x + o1 * wl.y);
      if (valid && fl == 0) {
        float z = rv + blin[0];
        fout[n] = 1.f / (1.f + __expf(-z));
      }
    } else {
      if (valid) out[(size_t)n * 32 + fl] = (f2bf(o1) << 16) | f2bf(o0);
    }
  }
}

extern "C" void kernel_launch(void* const* d_in, const int* in_sizes, int n_in,
                              void* d_out, int out_size, void* d_ws, size_t ws_size,
                              hipStream_t stream) {
  const float* x   = (const float*)d_in[0];
  const int*   ei  = (const int*)d_in[1];
  const float* W1  = (const float*)d_in[2];
  const float* a1s = (const float*)d_in[3];
  const float* a1d = (const float*)d_in[4];
  const float* b1  = (const float*)d_in[5];
  const float* W2  = (const float*)d_in[6];
  const float* a2s = (const float*)d_in[7];
  const float* a2d = (const float*)d_in[8];
  const float* b2  = (const float*)d_in[9];
  const float* W3  = (const float*)d_in[10];
  const float* a3s = (const float*)d_in[11];
  const float* a3d = (const float*)d_in[12];
  const float* b3  = (const float*)d_in[13];
  const float* Wl  = (const float*)d_in[14];
  const float* bl  = (const float*)d_in[15];

  const int N  = in_sizes[0] / 128;
  const int E  = in_sizes[1] / 2;
  const int EE = E + N;
  const int nbk = (N + 255) >> 8;

  char* p = (char*)d_ws;
  auto alloc = [&](size_t bytes) { char* r = p; p += (bytes + 255) & ~(size_t)255; return r; };
  unsigned* gbucket = (unsigned*)alloc((size_t)MAXBK * 4);
  unsigned* bbase   = (unsigned*)alloc((size_t)(MAXBK + 1) * 4);
  unsigned* bfill   = (unsigned*)alloc((size_t)MAXBK * 4);
  short8*   wf      = (short8*)alloc(2048 * 16);
  int*      rowptr  = (int*)alloc((size_t)(N + 1) * 4);
  int*      csr_src = (int*)alloc((size_t)EE * 4);
  unsigned* hbuf    = (unsigned*)alloc((size_t)N * 32 * 4);   // bf16-pair packed
  char*     regionA = alloc((size_t)EE * 8);                  // part[] then obuf
  float*    as_     = (float*)alloc((size_t)N * 4);
  float*    ad_     = (float*)alloc((size_t)N * 4);

  uint2*    part = (uint2*)regionA;            // CSR build scratch
  unsigned* obuf = (unsigned*)regionA;         // bf16-pair packed layer io

  hipMemsetAsync(gbucket, 0, (size_t)MAXBK * 4, stream);

  k_wprep<<<8, 256, 0, stream>>>(W1, W2, W3, wf);
  k_bhist<<<256, 256, 0, stream>>>(ei, gbucket, E, nbk);
  k_bscan<<<1, 256, 0, stream>>>(gbucket, bbase, bfill, nbk, EE, N);
  k_part<<<(EE + PCHUNK - 1) / PCHUNK, 256, 0, stream>>>(ei, bfill, part, E, EE);
  k_bcsr<<<nbk, 256, 0, stream>>>(part, bbase, rowptr, csr_src, N, nbk);

  int ntile64 = (N + 63) / 64;
  int g1 = ntile64 < 512 ? ntile64 : 512;
  int g2 = ntile64 < 768 ? ntile64 : 768;
  int nb = (N + 7) / 8;

  // layer 1 (f32 x input, K=128)
  k_gemm8<128, true><<<g1, 128, 0, stream>>>(x, wf, a1s, a1d, hbuf, as_, ad_, N, ntile64);
  k_agg11<0><<<nb, 256, 0, stream>>>(rowptr, csr_src, hbuf, as_, ad_, b1, obuf,
                                     nullptr, nullptr, nullptr, N);
  // layer 2 (bf16 obuf input, K=64)
  k_gemm8<64, false><<<g2, 128, 0, stream>>>(obuf, wf + 16 * 64, a2s, a2d,
                                             hbuf, as_, ad_, N, ntile64);
  k_agg11<0><<<nb, 256, 0, stream>>>(rowptr, csr_src, hbuf, as_, ad_, b2, obuf,
                                     nullptr, nullptr, nullptr, N);
  // layer 3 (+ fused readout)
  k_gemm8<64, false><<<g2, 128, 0, stream>>>(obuf, wf + 24 * 64, a3s, a3d,
                                             hbuf, as_, ad_, N, ntile64);
  k_agg11<1><<<nb, 256, 0, stream>>>(rowptr, csr_src, hbuf, as_, ad_, b3, nullptr,
                                     Wl, bl, (float*)d_out, N);
}